// Round 13
// baseline (1061.873 us; speedup 1.0000x reference)
//
#include <hip/hip_runtime.h>
#include <hip/hip_fp16.h>
#include <math.h>

#define NN 40000
#define EE 200000
#define DD 32
#define ND (NN * DD)        // 1,280,000
#define LNEPS 1e-5f

typedef float    fv4 __attribute__((ext_vector_type(4)));
typedef unsigned uv4 __attribute__((ext_vector_type(4)));

// scal slots — separate cache lines for atomically-updated slots
#define SLOT_S1    0    // u4 . u5
#define SLOT_S2    32   // u4 . u4
#define SLOT_ALPHA 48   // 2 / (lam + eps)

__device__ __forceinline__ void threefry2x32(unsigned k0, unsigned k1,
                                             unsigned x0, unsigned x1,
                                             unsigned& o0, unsigned& o1) {
  const unsigned k2 = k0 ^ k1 ^ 0x1BD11BDAu;
  unsigned v0 = x0 + k0, v1 = x1 + k1;
#define TF_ROUND(r) { v0 += v1; v1 = (v1 << (r)) | (v1 >> (32 - (r))); v1 ^= v0; }
  TF_ROUND(13) TF_ROUND(15) TF_ROUND(26) TF_ROUND(6)
  v0 += k1; v1 += k2 + 1u;
  TF_ROUND(17) TF_ROUND(29) TF_ROUND(16) TF_ROUND(24)
  v0 += k2; v1 += k0 + 2u;
  TF_ROUND(13) TF_ROUND(15) TF_ROUND(26) TF_ROUND(6)
  v0 += k0; v1 += k1 + 3u;
  TF_ROUND(17) TF_ROUND(29) TF_ROUND(16) TF_ROUND(24)
  v0 += k1; v1 += k2 + 4u;
  TF_ROUND(13) TF_ROUND(15) TF_ROUND(26) TF_ROUND(6)
  v0 += k2; v1 += k0 + 5u;
#undef TF_ROUND
  o0 = v0; o1 = v1;
}

__device__ __forceinline__ float wave64_sum(float x) {
  for (int o = 32; o > 0; o >>= 1) x += __shfl_xor(x, o, 64);
  return x;
}
__device__ __forceinline__ float g32_sum(float x) {
  for (int o = 16; o > 0; o >>= 1) x += __shfl_xor(x, o, 32);
  return x;
}

// deg (float, both endpoints) + hist (int, row occurrences)
__global__ void k_deg(const int* __restrict__ ei, float* __restrict__ deg,
                      int* __restrict__ hist) {
  int e = blockIdx.x * 256 + threadIdx.x;
  if (e < EE) {
    int r = ei[e];
    atomicAdd(deg + r, 1.0f);
    atomicAdd(deg + ei[EE + e], 1.0f);
    atomicAdd(hist + r, 1);
  }
}

// single-block exclusive scan over hist[NN] -> row_start[NN+1], cursor[NN]
__global__ __launch_bounds__(1024) void k_scan(const int* __restrict__ hist,
                                               int* __restrict__ row_start,
                                               int* __restrict__ cursor) {
  __shared__ int part[1024];
  const int t = threadIdx.x;
  const int base = t * 40;
  int s = 0;
  for (int i = base; i < base + 40 && i < NN; ++i) s += hist[i];
  part[t] = s;
  __syncthreads();
  for (int off = 1; off < 1024; off <<= 1) {
    int v = (t >= off) ? part[t - off] : 0;
    __syncthreads();
    part[t] += v;
    __syncthreads();
  }
  int ex = (t == 0) ? 0 : part[t - 1];
  for (int i = base; i < base + 40 && i < NN; ++i) {
    row_start[i] = ex;
    cursor[i] = ex;
    ex += hist[i];
  }
  if (t == 0) row_start[NN] = EE;
}

// v0 = N(0,1) via exact JAX threefry pipeline; normalization deferred.
__global__ void k_genv(float* __restrict__ v) {
  int i = blockIdx.x * 256 + threadIdx.x;
  unsigned o0, o1;
  threefry2x32(0u, 42u, 0u, (unsigned)i, o0, o1);
  unsigned bits = o1;
  float f = __uint_as_float((bits >> 9) | 0x3f800000u) - 1.0f;
  const float lo = -0.99999994f;
  float u = fmaxf(lo, f * 2.0f + lo);
  v[i] = 1.41421354f * erfinvf(u);
}

__device__ __forceinline__ int clamp8(float q) {
  int v = (int)rintf(q);
  return v < -127 ? -127 : (v > 127 ? 127 : v);
}
__device__ __forceinline__ unsigned pack4v(fv4 q, float inv) {
  int q0 = clamp8(q.x * inv), q1 = clamp8(q.y * inv),
      q2 = clamp8(q.z * inv), q3 = clamp8(q.w * inv);
  return (q0 & 255) | ((q1 & 255) << 8) | ((q2 & 255) << 16) | ((q3 & 255) << 24);
}
__device__ __forceinline__ void dp4(unsigned u, fv4 xv, float& acc) {
  acc = fmaf((float)(signed char)(u),        xv.x, acc);
  acc = fmaf((float)(signed char)(u >> 8),   xv.y, acc);
  acc = fmaf((float)(signed char)(u >> 16),  xv.z, acc);
  acc = fmaf((float)(signed char)(u >> 24),  xv.w, acc);
}

// Fused: Q -> int8 sorted-CSR conversion AND first power sweep (f32 dot,
// atomic scatter of -Q.x into out which k_pre pre-filled with deg*x).
// Qi8/Qs written NONTEMPORAL so the 218 MB copy doesn't flush x from L2/L3.
__global__ __launch_bounds__(256) void k_cvt_mv(const float* __restrict__ x,
                                                const float* __restrict__ Q,
                                                const int* __restrict__ ei,
                                                int* __restrict__ cursor,
                                                char* __restrict__ Qi8,
                                                __half* __restrict__ Qs,
                                                int* __restrict__ cols,
                                                float* __restrict__ out) {
  const int slot = threadIdx.x >> 5;
  const int lane = threadIdx.x & 31;
  const int e = blockIdx.x * 8 + slot;  // EE % 8 == 0
  const int row = ei[e];
  const int col = ei[EE + e];
  int pos = 0;
  if (lane == 0) pos = atomicAdd(cursor + row, 1);
  pos = __shfl(pos, 0, 32);
  const fv4* __restrict__ x4 = (const fv4*)(x + (size_t)col * DD);
  fv4 xr[8];
#pragma unroll
  for (int k = 0; k < 8; ++k) xr[k] = x4[k];
  const fv4* __restrict__ q4 =
      (const fv4*)(Q + (size_t)e * (DD * DD) + (size_t)lane * DD);
  fv4 qf[8];
#pragma unroll
  for (int k = 0; k < 8; ++k) qf[k] = __builtin_nontemporal_load(q4 + k);
  // f32 dot (power sweep 1 — exact)
  float acc = 0.0f;
#pragma unroll
  for (int k = 0; k < 8; ++k) {
    acc = fmaf(qf[k].x, xr[k].x, acc);
    acc = fmaf(qf[k].y, xr[k].y, acc);
    acc = fmaf(qf[k].z, xr[k].z, acc);
    acc = fmaf(qf[k].w, xr[k].w, acc);
  }
  // int8 quantization (per-row fp16 scale)
  float m = 0.0f;
#pragma unroll
  for (int k = 0; k < 8; ++k) {
    m = fmaxf(m, fmaxf(fmaxf(fabsf(qf[k].x), fabsf(qf[k].y)),
                       fmaxf(fabsf(qf[k].z), fabsf(qf[k].w))));
  }
  __half sh = __float2half(m * (1.0f / 127.0f));
  float s = __half2float(sh);
  float inv = (s > 0.0f) ? 1.0f / s : 0.0f;
  uv4 pa, pb;
  pa.x = pack4v(qf[0], inv); pa.y = pack4v(qf[1], inv);
  pa.z = pack4v(qf[2], inv); pa.w = pack4v(qf[3], inv);
  pb.x = pack4v(qf[4], inv); pb.y = pack4v(qf[5], inv);
  pb.z = pack4v(qf[6], inv); pb.w = pack4v(qf[7], inv);
  uv4* __restrict__ qs = (uv4*)(Qi8 + (size_t)pos * (DD * DD) + (size_t)lane * DD);
  __builtin_nontemporal_store(pa, qs);
  __builtin_nontemporal_store(pb, qs + 1);
  unsigned short shb = *(unsigned short*)&sh;
  __builtin_nontemporal_store(shb, (unsigned short*)(Qs + pos * DD + lane));
  if (lane == 0) cols[pos] = col;
  atomicAdd(out + (size_t)row * DD + lane, -acc);
}

#define CHUNK 16

// Gather matvec, one wave64 per row, 2 edges/iter, depth-2 Q prefetch.
// Qi8/Qs loads are NONTEMPORAL (stream must not evict x from L2/L3);
// x loads stay cached.
// mode 0: out = deg*x - off
// mode 1: out = alpha*(deg*x - off) - x
// mode 2: out = 2*alpha*(deg*x - off) - 2x - xprev
__global__ __launch_bounds__(256) void k_gather(const float* __restrict__ x,
                                                const float* __restrict__ xprev,
                                                const char* __restrict__ Qi8,
                                                const __half* __restrict__ Qs,
                                                const int* __restrict__ cols,
                                                const int* __restrict__ row_start,
                                                const float* __restrict__ deg,
                                                const float* __restrict__ scal,
                                                float* __restrict__ out, int mode) {
  __shared__ float lds[4][CHUNK][DD];    // 8 KB
  const int wid  = threadIdx.x >> 6;
  const int lane = threadIdx.x & 63;
  const int half = lane >> 5;
  const int d    = lane & 31;
  const int r = blockIdx.x * 4 + wid;    // NN % 4 == 0
  const int beg = row_start[r];
  const int end = row_start[r + 1];
  const int degree = end - beg;

  // hoisted epilogue operands
  const size_t idx = (size_t)r * DD + d;
  const float xi = x[idx];
  const float dv = deg[r];
  const float xp = (mode == 2) ? xprev[idx] : 0.0f;

  float acc = 0.0f;
  for (int chunk = 0; chunk < degree; chunk += CHUNK) {
    const int nchunk = min(CHUNK, degree - chunk);
    int myc = (lane < nchunk) ? cols[beg + chunk + lane] : 0;
    // stage x rows into LDS: lane l covers edge l>>2, floats (l&3)*8..+7
    {
      const int el = lane >> 2;
      const int pt = lane & 3;
      if (el < nchunk) {
        const int c = __shfl(myc, el, 64);
        const fv4* __restrict__ xs = (const fv4*)(x + (size_t)c * DD);
        fv4 a = xs[pt * 2];
        fv4 b = xs[pt * 2 + 1];
        fv4* __restrict__ dst = (fv4*)&lds[wid][el][pt * 8];
        dst[0] = a;
        dst[1] = b;
      }
    }
    // depth-2 software pipeline on Q pairs (nontemporal stream)
    uv4 a0 = {0,0,0,0}, b0 = {0,0,0,0}, a1 = {0,0,0,0}, b1 = {0,0,0,0};
    float s0 = 0.0f, s1 = 0.0f;
#define LOADQ(PP, A, B, S)                                                    \
    if ((PP) < nchunk) {                                                      \
      const size_t pos = (size_t)(beg + chunk + (PP));                        \
      const uv4* __restrict__ q8 =                                            \
          (const uv4*)(Qi8 + pos * (DD * DD) + (size_t)d * DD);               \
      A = __builtin_nontemporal_load(q8);                                     \
      B = __builtin_nontemporal_load(q8 + 1);                                 \
      unsigned short sb = __builtin_nontemporal_load(                         \
          (const unsigned short*)(Qs + pos * DD + d));                        \
      S = __half2float(*(__half*)&sb);                                       \
    }
    LOADQ(half, a0, b0, s0)
    LOADQ(2 + half, a1, b1, s1)
    for (int p0 = 0; p0 < nchunk; p0 += 2) {
      uv4 a2 = {0,0,0,0}, b2 = {0,0,0,0};
      float s2 = 0.0f;
      LOADQ(p0 + 4 + half, a2, b2, s2)
      const int p = p0 + half;
      if (p < nchunk) {
        const fv4* __restrict__ xl = (const fv4*)&lds[wid][p][0];
        fv4 xr[8];
#pragma unroll
        for (int k = 0; k < 8; ++k) xr[k] = xl[k];
        float dot = 0.0f;
        dp4(a0.x, xr[0], dot); dp4(a0.y, xr[1], dot);
        dp4(a0.z, xr[2], dot); dp4(a0.w, xr[3], dot);
        dp4(b0.x, xr[4], dot); dp4(b0.y, xr[5], dot);
        dp4(b0.z, xr[6], dot); dp4(b0.w, xr[7], dot);
        acc = fmaf(s0, dot, acc);
      }
      a0 = a1; b0 = b1; s0 = s1;
      a1 = a2; b1 = b2; s1 = s2;
    }
#undef LOADQ
  }
  acc += __shfl_xor(acc, 32, 64);

  if (half == 0) {
    float o;
    if (mode == 0)      o = dv * xi - acc;
    else if (mode == 1) o = scal[SLOT_ALPHA] * (dv * xi - acc) - xi;
    else                o = 2.0f * scal[SLOT_ALPHA] * (dv * xi - acc)
                            - 2.0f * xi - xp;
    out[idx] = o;
  }
}

// out = diag part — used before scatter matvec (cvt fusion + fallback).
__global__ void k_pre(const float* __restrict__ x, const float* __restrict__ xprev,
                      const float* __restrict__ deg, const float* __restrict__ scal,
                      float* __restrict__ out, int mode) {
  int i = blockIdx.x * 256 + threadIdx.x;
  float d = deg[i >> 5];
  float xi = x[i];
  if (mode == 0)       out[i] = d * xi;
  else if (mode == 1)  out[i] = scal[SLOT_ALPHA] * d * xi - xi;
  else                 out[i] = 2.0f * scal[SLOT_ALPHA] * d * xi - 2.0f * xi - xprev[i];
}

// f32 fallback matvec (only if ws too small)
__global__ __launch_bounds__(256) void k_matvec(const float* __restrict__ x,
                                                const float* __restrict__ Q,
                                                const int* __restrict__ ei,
                                                float* __restrict__ out,
                                                const float* __restrict__ scal,
                                                int use_alpha, float smul) {
  const int slot = threadIdx.x >> 5;
  const int lane = threadIdx.x & 31;
  const int e = blockIdx.x * 8 + slot;
  const float factor = use_alpha ? scal[SLOT_ALPHA] * smul : smul;
  const int row = ei[e];
  const int col = ei[EE + e];
  const fv4* __restrict__ x4 = (const fv4*)(x + (size_t)col * DD);
  fv4 xr[8];
#pragma unroll
  for (int k = 0; k < 8; ++k) xr[k] = x4[k];
  const fv4* __restrict__ q4 =
      (const fv4*)(Q + (size_t)e * (DD * DD) + (size_t)lane * DD);
  float acc = 0.0f;
#pragma unroll
  for (int k = 0; k < 8; ++k) {
    fv4 q = q4[k];
    acc = fmaf(q.x, xr[k].x, acc);
    acc = fmaf(q.y, xr[k].y, acc);
    acc = fmaf(q.z, xr[k].z, acc);
    acc = fmaf(q.w, xr[k].w, acc);
  }
  atomicAdd(out + (size_t)row * DD + lane, -factor * acc);
}

#define DOT_BLOCKS 640
__global__ void k_dots(const float* __restrict__ u4, const float* __restrict__ u5,
                       float* __restrict__ scal) {
  float s1 = 0.0f, s2 = 0.0f;
  for (int i = blockIdx.x * 256 + threadIdx.x; i < ND; i += DOT_BLOCKS * 256) {
    float a = u4[i], b = u5[i];
    s1 = fmaf(a, b, s1);
    s2 = fmaf(a, a, s2);
  }
  s1 = wave64_sum(s1);
  s2 = wave64_sum(s2);
  __shared__ float ls1[4], ls2[4];
  int w = threadIdx.x >> 6;
  if ((threadIdx.x & 63) == 0) { ls1[w] = s1; ls2[w] = s2; }
  __syncthreads();
  if (threadIdx.x == 0) {
    atomicAdd(scal + SLOT_S1, ls1[0] + ls1[1] + ls1[2] + ls1[3]);
    atomicAdd(scal + SLOT_S2, ls2[0] + ls2[1] + ls2[2] + ls2[3]);
  }
}

__global__ void k_alpha(float* __restrict__ scal) {
  float lam = scal[SLOT_S1] / scal[SLOT_S2] / (1.0f + 1e-8f);
  lam = fmaxf(lam, 1.0f);
  scal[SLOT_ALPHA] = 2.0f / (lam + 1e-8f);
}

__global__ __launch_bounds__(256) void k_fuse(
    const float* __restrict__ h,
    const float* __restrict__ T1, const float* __restrict__ T2,
    const float* __restrict__ T3, const float* __restrict__ T4,
    const float* __restrict__ coeffs,
    const float* __restrict__ projW, const float* __restrict__ projb,
    const float* __restrict__ projg, const float* __restrict__ projbeta,
    const float* __restrict__ fusW1, const float* __restrict__ fusb1,
    const float* __restrict__ fusg, const float* __restrict__ fusbeta,
    const float* __restrict__ fusW2, const float* __restrict__ fusb2,
    float* __restrict__ out) {
  __shared__ float s_res[8][3][DD];
  __shared__ float s_p[8][3 * DD];
  __shared__ float s_s[8][DD];
  const int slot = threadIdx.x >> 5;
  const int lane = threadIdx.x & 31;
  const int n = blockIdx.x * 8 + slot;

  float w[3][5];
#pragma unroll
  for (int b = 0; b < 3; ++b) {
    float m = -1e30f;
#pragma unroll
    for (int k = 0; k < 5; ++k) m = fmaxf(m, coeffs[b * 5 + k]);
    float s = 0.0f;
#pragma unroll
    for (int k = 0; k < 5; ++k) { w[b][k] = expf(coeffs[b * 5 + k] - m); s += w[b][k]; }
#pragma unroll
    for (int k = 0; k < 5; ++k) w[b][k] /= s;
  }

  const int idx = n * DD + lane;
  float hd = h[idx], t1 = T1[idx], t2 = T2[idx], t3 = T3[idx], t4 = T4[idx];
#pragma unroll
  for (int b = 0; b < 3; ++b)
    s_res[slot][b][lane] =
        w[b][0] * hd + w[b][1] * t1 + w[b][2] * t2 + w[b][3] * t3 + w[b][4] * t4;
  __syncthreads();

#pragma unroll
  for (int b = 0; b < 3; ++b) {
    float y = projb[b * DD + lane];
#pragma unroll
    for (int j = 0; j < DD; ++j)
      y = fmaf(s_res[slot][b][j], projW[(b * DD + j) * DD + lane], y);
    float mu = g32_sum(y) * (1.0f / DD);
    float d = y - mu;
    float var = g32_sum(d * d) * (1.0f / DD);
    float z = d * rsqrtf(var + LNEPS) * projg[b * DD + lane] + projbeta[b * DD + lane];
    float pb = z / (1.0f + expf(-z));
    s_p[slot][b * DD + lane] = pb;
  }
  __syncthreads();

  float y = fusb1[lane];
#pragma unroll
  for (int j = 0; j < 3 * DD; ++j)
    y = fmaf(s_p[slot][j], fusW1[j * DD + lane], y);
  float mu = g32_sum(y) * (1.0f / DD);
  float d = y - mu;
  float var = g32_sum(d * d) * (1.0f / DD);
  float z = d * rsqrtf(var + LNEPS) * fusg[lane] + fusbeta[lane];
  float sv = z / (1.0f + expf(-z));
  s_s[slot][lane] = sv;
  __syncthreads();

  float o = fusb2[lane];
#pragma unroll
  for (int j = 0; j < DD; ++j)
    o = fmaf(s_s[slot][j], fusW2[j * DD + lane], o);
  out[idx] = hd + o;
}

extern "C" void kernel_launch(void* const* d_in, const int* in_sizes, int n_in,
                              void* d_out, int out_size, void* d_ws, size_t ws_size,
                              hipStream_t stream) {
  (void)in_sizes; (void)n_in; (void)out_size;
  const float* h        = (const float*)d_in[0];
  const float* Q        = (const float*)d_in[1];
  const int*   ei       = (const int*)d_in[2];
  const float* coeffs   = (const float*)d_in[3];
  const float* projW    = (const float*)d_in[4];
  const float* projb    = (const float*)d_in[5];
  const float* projg    = (const float*)d_in[6];
  const float* projbeta = (const float*)d_in[7];
  const float* fusW1    = (const float*)d_in[8];
  const float* fusb1    = (const float*)d_in[9];
  const float* fusg     = (const float*)d_in[10];
  const float* fusbeta  = (const float*)d_in[11];
  const float* fusW2    = (const float*)d_in[12];
  const float* fusb2    = (const float*)d_in[13];
  float* out = (float*)d_out;

  // workspace layout
  const size_t qi_bytes  = (size_t)EE * DD * DD;              // 204.8 MB
  const size_t qs_bytes  = (size_t)EE * DD * sizeof(__half);  // 12.8 MB
  const size_t col_bytes = (size_t)EE * sizeof(int);
  const size_t idx_bytes = (size_t)(2 * NN + 2) * sizeof(int);
  const size_t f32_elems = 6u * (size_t)ND + 2u * NN + 64;    // incl hist
  const size_t meta = qi_bytes + qs_bytes + col_bytes + idx_bytes;
  const size_t need = meta + f32_elems * sizeof(float) + 512;
  const bool fast = ws_size >= need;

  char*   Qi8 = (char*)d_ws;
  __half* Qs  = (__half*)((char*)d_ws + qi_bytes);
  int*  cols      = (int*)((char*)d_ws + qi_bytes + qs_bytes);
  int*  row_start = cols + EE;
  int*  cursor    = row_start + NN + 1;
  float* base = fast
      ? (float*)((char*)d_ws + ((meta + 255) & ~(size_t)255))
      : (float*)d_ws;
  float* uA   = base;
  float* uB   = uA + ND;
  float* T1   = uB + ND;
  float* T2   = T1 + ND;
  float* T3   = T2 + ND;
  float* T4   = T3 + ND;
  float* deg  = T4 + ND;              // [NN]
  float* scal = deg + NN;             // [64]
  int*   hist = (int*)(scal + 64);    // [NN]

  (void)hipMemsetAsync(deg, 0, (2 * (size_t)NN + 64) * sizeof(float), stream);

  k_deg<<<(EE + 255) / 256, 256, 0, stream>>>(ei, deg, hist);
  k_genv<<<ND / 256, 256, 0, stream>>>(uA);

  if (fast) {
    k_scan<<<1, 1024, 0, stream>>>(hist, row_start, cursor);
    // sweep 1 fused with conversion: uB = deg*uA - Q.uA (f32-exact)
    k_pre<<<ND / 256, 256, 0, stream>>>(uA, nullptr, deg, scal, uB, 0);
    k_cvt_mv<<<EE / 8, 256, 0, stream>>>(uA, Q, ei, cursor, Qi8, Qs, cols, uB);

    // power sweeps 2..5 (int8 gather, nt stream): uB -> uA -> uB -> uA -> uB
    k_gather<<<NN / 4, 256, 0, stream>>>(uB, nullptr, Qi8, Qs, cols,
                                         row_start, deg, scal, uA, 0);
    k_gather<<<NN / 4, 256, 0, stream>>>(uA, nullptr, Qi8, Qs, cols,
                                         row_start, deg, scal, uB, 0);
    k_gather<<<NN / 4, 256, 0, stream>>>(uB, nullptr, Qi8, Qs, cols,
                                         row_start, deg, scal, uA, 0);
    k_gather<<<NN / 4, 256, 0, stream>>>(uA, nullptr, Qi8, Qs, cols,
                                         row_start, deg, scal, uB, 0);
    // u4 = uA, u5 = uB
    k_dots<<<DOT_BLOCKS, 256, 0, stream>>>(uA, uB, scal);
    k_alpha<<<1, 1, 0, stream>>>(scal);

    // Chebyshev: T1 = alpha*L h - h ; T_next = 2*(alpha*L x - x) - xprev
    const float* xin[4]   = {h, T1, T2, T3};
    const float* prevs[4] = {h, h, T1, T2};
    float* touts[4]       = {T1, T2, T3, T4};
    for (int k = 0; k < 4; ++k) {
      k_gather<<<NN / 4, 256, 0, stream>>>(xin[k], prevs[k], Qi8, Qs, cols,
                                           row_start, deg, scal, touts[k],
                                           k == 0 ? 1 : 2);
    }
  } else {
    // f32 atomic-scatter fallback
    float* cur = uA;
    float* nxt = uB;
    for (int it = 0; it < 5; ++it) {
      k_pre<<<ND / 256, 256, 0, stream>>>(cur, nullptr, deg, scal, nxt, 0);
      k_matvec<<<EE / 8, 256, 0, stream>>>(cur, Q, ei, nxt, scal, 0, 1.0f);
      float* t = cur; cur = nxt; nxt = t;
    }
    k_dots<<<DOT_BLOCKS, 256, 0, stream>>>(nxt, cur, scal);
    k_alpha<<<1, 1, 0, stream>>>(scal);
    const float* xin[4]   = {h, T1, T2, T3};
    const float* prevs[4] = {nullptr, h, T1, T2};
    float* touts[4]       = {T1, T2, T3, T4};
    for (int k = 0; k < 4; ++k) {
      k_pre<<<ND / 256, 256, 0, stream>>>(xin[k], prevs[k], deg, scal, touts[k],
                                          k == 0 ? 1 : 2);
      k_matvec<<<EE / 8, 256, 0, stream>>>(xin[k], Q, ei, touts[k], scal, 1,
                                           k == 0 ? 1.0f : 2.0f);
    }
  }

  k_fuse<<<NN / 8, 256, 0, stream>>>(h, T1, T2, T3, T4, coeffs,
                                     projW, projb, projg, projbeta,
                                     fusW1, fusb1, fusg, fusbeta,
                                     fusW2, fusb2, out);
}

// Round 14
// 939.541 us; speedup vs baseline: 1.1302x; 1.1302x over previous
//
#include <hip/hip_runtime.h>
#include <hip/hip_fp16.h>
#include <math.h>

#define NN 40000
#define EE 200000
#define DD 32
#define ND (NN * DD)        // 1,280,000
#define LNEPS 1e-5f

typedef float    fv4 __attribute__((ext_vector_type(4)));
typedef unsigned uv4 __attribute__((ext_vector_type(4)));

// scal layout: [48]=alpha; dot leaves: s1 at 64+l*32, s2 at 64+1024+l*32
#define SLOT_ALPHA 48
#define SCAL_FLOATS (64 + 2048 + 64)

__device__ __forceinline__ void threefry2x32(unsigned k0, unsigned k1,
                                             unsigned x0, unsigned x1,
                                             unsigned& o0, unsigned& o1) {
  const unsigned k2 = k0 ^ k1 ^ 0x1BD11BDAu;
  unsigned v0 = x0 + k0, v1 = x1 + k1;
#define TF_ROUND(r) { v0 += v1; v1 = (v1 << (r)) | (v1 >> (32 - (r))); v1 ^= v0; }
  TF_ROUND(13) TF_ROUND(15) TF_ROUND(26) TF_ROUND(6)
  v0 += k1; v1 += k2 + 1u;
  TF_ROUND(17) TF_ROUND(29) TF_ROUND(16) TF_ROUND(24)
  v0 += k2; v1 += k0 + 2u;
  TF_ROUND(13) TF_ROUND(15) TF_ROUND(26) TF_ROUND(6)
  v0 += k0; v1 += k1 + 3u;
  TF_ROUND(17) TF_ROUND(29) TF_ROUND(16) TF_ROUND(24)
  v0 += k1; v1 += k2 + 4u;
  TF_ROUND(13) TF_ROUND(15) TF_ROUND(26) TF_ROUND(6)
  v0 += k2; v1 += k0 + 5u;
#undef TF_ROUND
  o0 = v0; o1 = v1;
}

__device__ __forceinline__ float wave64_sum(float x) {
  for (int o = 32; o > 0; o >>= 1) x += __shfl_xor(x, o, 64);
  return x;
}
__device__ __forceinline__ float g32_sum(float x) {
  for (int o = 16; o > 0; o >>= 1) x += __shfl_xor(x, o, 32);
  return x;
}

// deg (float, both endpoints) + hist (int, row occurrences)
__global__ void k_deg(const int* __restrict__ ei, float* __restrict__ deg,
                      int* __restrict__ hist) {
  int e = blockIdx.x * 256 + threadIdx.x;
  if (e < EE) {
    int r = ei[e];
    atomicAdd(deg + r, 1.0f);
    atomicAdd(deg + ei[EE + e], 1.0f);
    atomicAdd(hist + r, 1);
  }
}

// single-block exclusive scan over hist[NN] -> row_start[NN+1], cursor[NN]
__global__ __launch_bounds__(1024) void k_scan(const int* __restrict__ hist,
                                               int* __restrict__ row_start,
                                               int* __restrict__ cursor) {
  __shared__ int part[1024];
  const int t = threadIdx.x;
  const int base = t * 40;
  int s = 0;
  for (int i = base; i < base + 40 && i < NN; ++i) s += hist[i];
  part[t] = s;
  __syncthreads();
  for (int off = 1; off < 1024; off <<= 1) {
    int v = (t >= off) ? part[t - off] : 0;
    __syncthreads();
    part[t] += v;
    __syncthreads();
  }
  int ex = (t == 0) ? 0 : part[t - 1];
  for (int i = base; i < base + 40 && i < NN; ++i) {
    row_start[i] = ex;
    cursor[i] = ex;
    ex += hist[i];
  }
  if (t == 0) row_start[NN] = EE;
}

// v0 = N(0,1) via exact JAX threefry pipeline; also pre-fills vpre = deg*v
// (the diag part of power sweep 1, which k_cvt_mv completes by scatter).
__global__ void k_genv(float* __restrict__ v, float* __restrict__ vpre,
                       const float* __restrict__ deg) {
  int i = blockIdx.x * 256 + threadIdx.x;
  unsigned o0, o1;
  threefry2x32(0u, 42u, 0u, (unsigned)i, o0, o1);
  unsigned bits = o1;
  float f = __uint_as_float((bits >> 9) | 0x3f800000u) - 1.0f;
  const float lo = -0.99999994f;
  float u = fmaxf(lo, f * 2.0f + lo);
  float val = 1.41421354f * erfinvf(u);
  v[i] = val;
  if (vpre) vpre[i] = deg[i >> 5] * val;
}

__device__ __forceinline__ int clamp8(float q) {
  int v = (int)rintf(q);
  return v < -127 ? -127 : (v > 127 ? 127 : v);
}
__device__ __forceinline__ unsigned pack4v(fv4 q, float inv) {
  int q0 = clamp8(q.x * inv), q1 = clamp8(q.y * inv),
      q2 = clamp8(q.z * inv), q3 = clamp8(q.w * inv);
  return (q0 & 255) | ((q1 & 255) << 8) | ((q2 & 255) << 16) | ((q3 & 255) << 24);
}
__device__ __forceinline__ void dp4(unsigned u, fv4 xv, float& acc) {
  acc = fmaf((float)(signed char)(u),        xv.x, acc);
  acc = fmaf((float)(signed char)(u >> 8),   xv.y, acc);
  acc = fmaf((float)(signed char)(u >> 16),  xv.z, acc);
  acc = fmaf((float)(signed char)(u >> 24),  xv.w, acc);
}

// Fused: Q -> int8 sorted-CSR conversion AND first power sweep (f32 dot,
// atomic scatter of -Q.x into out pre-filled with deg*x by k_genv).
__global__ __launch_bounds__(256) void k_cvt_mv(const float* __restrict__ x,
                                                const float* __restrict__ Q,
                                                const int* __restrict__ ei,
                                                int* __restrict__ cursor,
                                                char* __restrict__ Qi8,
                                                __half* __restrict__ Qs,
                                                int* __restrict__ cols,
                                                float* __restrict__ out) {
  const int slot = threadIdx.x >> 5;
  const int lane = threadIdx.x & 31;
  const int e = blockIdx.x * 8 + slot;  // EE % 8 == 0
  const int row = ei[e];
  const int col = ei[EE + e];
  int pos = 0;
  if (lane == 0) pos = atomicAdd(cursor + row, 1);
  pos = __shfl(pos, 0, 32);
  const fv4* __restrict__ x4 = (const fv4*)(x + (size_t)col * DD);
  fv4 xr[8];
#pragma unroll
  for (int k = 0; k < 8; ++k) xr[k] = x4[k];
  const fv4* __restrict__ q4 =
      (const fv4*)(Q + (size_t)e * (DD * DD) + (size_t)lane * DD);
  fv4 qf[8];
#pragma unroll
  for (int k = 0; k < 8; ++k) qf[k] = __builtin_nontemporal_load(q4 + k);
  // f32 dot (power sweep 1 — exact)
  float acc = 0.0f;
#pragma unroll
  for (int k = 0; k < 8; ++k) {
    acc = fmaf(qf[k].x, xr[k].x, acc);
    acc = fmaf(qf[k].y, xr[k].y, acc);
    acc = fmaf(qf[k].z, xr[k].z, acc);
    acc = fmaf(qf[k].w, xr[k].w, acc);
  }
  // int8 quantization (per-row fp16 scale)
  float m = 0.0f;
#pragma unroll
  for (int k = 0; k < 8; ++k) {
    m = fmaxf(m, fmaxf(fmaxf(fabsf(qf[k].x), fabsf(qf[k].y)),
                       fmaxf(fabsf(qf[k].z), fabsf(qf[k].w))));
  }
  __half sh = __float2half(m * (1.0f / 127.0f));
  float s = __half2float(sh);
  float inv = (s > 0.0f) ? 1.0f / s : 0.0f;
  uv4 pa, pb;
  pa.x = pack4v(qf[0], inv); pa.y = pack4v(qf[1], inv);
  pa.z = pack4v(qf[2], inv); pa.w = pack4v(qf[3], inv);
  pb.x = pack4v(qf[4], inv); pb.y = pack4v(qf[5], inv);
  pb.z = pack4v(qf[6], inv); pb.w = pack4v(qf[7], inv);
  uv4* __restrict__ qs = (uv4*)(Qi8 + (size_t)pos * (DD * DD) + (size_t)lane * DD);
  qs[0] = pa;   // cached — later sweeps get ~45% L3 hits on this copy (r13 lesson)
  qs[1] = pb;
  Qs[pos * DD + lane] = sh;
  if (lane == 0) cols[pos] = col;
  atomicAdd(out + (size_t)row * DD + lane, -acc);
}

#define CHUNK 16

// Gather matvec, one wave64 per row, 2 edges/iter, depth-2 Q prefetch.
// mode 0: out = deg*x - off
// mode 1: out = alpha*(deg*x - off) - x
// mode 2: out = 2*alpha*(deg*x - off) - 2x - xprev
// mode 3: mode 0 + fused dot products (s1 += out.x, s2 += x.x) into leaf slots
__global__ __launch_bounds__(256) void k_gather(const float* __restrict__ x,
                                                const float* __restrict__ xprev,
                                                const char* __restrict__ Qi8,
                                                const __half* __restrict__ Qs,
                                                const int* __restrict__ cols,
                                                const int* __restrict__ row_start,
                                                const float* __restrict__ deg,
                                                const float* __restrict__ scal,
                                                float* __restrict__ dots,
                                                float* __restrict__ out, int mode) {
  __shared__ float lds[4][CHUNK][DD];    // 8 KB
  __shared__ float d1[4], d2[4];
  const int wid  = threadIdx.x >> 6;
  const int lane = threadIdx.x & 63;
  const int half = lane >> 5;
  const int d    = lane & 31;
  const int r = blockIdx.x * 4 + wid;    // NN % 4 == 0
  const int beg = row_start[r];
  const int end = row_start[r + 1];
  const int degree = end - beg;

  // hoisted epilogue operands
  const size_t idx = (size_t)r * DD + d;
  const float xi = x[idx];
  const float dv = deg[r];
  const float xp = (mode == 2) ? xprev[idx] : 0.0f;

  float acc = 0.0f;
  for (int chunk = 0; chunk < degree; chunk += CHUNK) {
    const int nchunk = min(CHUNK, degree - chunk);
    int myc = (lane < nchunk) ? cols[beg + chunk + lane] : 0;
    // stage x rows into LDS: lane l covers edge l>>2, floats (l&3)*8..+7
    {
      const int el = lane >> 2;
      const int pt = lane & 3;
      if (el < nchunk) {
        const int c = __shfl(myc, el, 64);
        const fv4* __restrict__ xs = (const fv4*)(x + (size_t)c * DD);
        fv4 a = xs[pt * 2];
        fv4 b = xs[pt * 2 + 1];
        fv4* __restrict__ dst = (fv4*)&lds[wid][el][pt * 8];
        dst[0] = a;
        dst[1] = b;
      }
    }
    // depth-2 software pipeline on Q pairs
    uv4 a0 = {0,0,0,0}, b0 = {0,0,0,0}, a1 = {0,0,0,0}, b1 = {0,0,0,0};
    float s0 = 0.0f, s1 = 0.0f;
#define LOADQ(PP, A, B, S)                                                    \
    if ((PP) < nchunk) {                                                      \
      const size_t pos = (size_t)(beg + chunk + (PP));                        \
      const uv4* __restrict__ q8 =                                            \
          (const uv4*)(Qi8 + pos * (DD * DD) + (size_t)d * DD);               \
      A = q8[0]; B = q8[1];                                                   \
      S = __half2float(Qs[pos * DD + d]);                                     \
    }
    LOADQ(half, a0, b0, s0)
    LOADQ(2 + half, a1, b1, s1)
    for (int p0 = 0; p0 < nchunk; p0 += 2) {
      uv4 a2 = {0,0,0,0}, b2 = {0,0,0,0};
      float s2 = 0.0f;
      LOADQ(p0 + 4 + half, a2, b2, s2)
      const int p = p0 + half;
      if (p < nchunk) {
        const fv4* __restrict__ xl = (const fv4*)&lds[wid][p][0];
        fv4 xr[8];
#pragma unroll
        for (int k = 0; k < 8; ++k) xr[k] = xl[k];
        float dot = 0.0f;
        dp4(a0.x, xr[0], dot); dp4(a0.y, xr[1], dot);
        dp4(a0.z, xr[2], dot); dp4(a0.w, xr[3], dot);
        dp4(b0.x, xr[4], dot); dp4(b0.y, xr[5], dot);
        dp4(b0.z, xr[6], dot); dp4(b0.w, xr[7], dot);
        acc = fmaf(s0, dot, acc);
      }
      a0 = a1; b0 = b1; s0 = s1;
      a1 = a2; b1 = b2; s1 = s2;
    }
#undef LOADQ
  }
  acc += __shfl_xor(acc, 32, 64);

  float o;
  if (mode == 1)      o = scal[SLOT_ALPHA] * (dv * xi - acc) - xi;
  else if (mode == 2) o = 2.0f * scal[SLOT_ALPHA] * (dv * xi - acc)
                          - 2.0f * xi - xp;
  else                o = dv * xi - acc;
  if (half == 0) out[idx] = o;

  if (mode == 3) {  // fused dots: s1 += u5.u4, s2 += u4.u4 (half-0 lanes only)
    float p1 = (half == 0) ? o * xi : 0.0f;
    float p2 = (half == 0) ? xi * xi : 0.0f;
    p1 = wave64_sum(p1);
    p2 = wave64_sum(p2);
    if ((threadIdx.x & 63) == 0) { d1[wid] = p1; d2[wid] = p2; }
    __syncthreads();
    if (threadIdx.x == 0) {
      const int leaf = blockIdx.x & 31;
      atomicAdd(dots + 64 + leaf * 32, d1[0] + d1[1] + d1[2] + d1[3]);
      atomicAdd(dots + 64 + 1024 + leaf * 32, d2[0] + d2[1] + d2[2] + d2[3]);
    }
  }
}

// out = diag part — fallback path only.
__global__ void k_pre(const float* __restrict__ x, const float* __restrict__ xprev,
                      const float* __restrict__ deg, const float* __restrict__ scal,
                      float* __restrict__ out, int mode) {
  int i = blockIdx.x * 256 + threadIdx.x;
  float d = deg[i >> 5];
  float xi = x[i];
  if (mode == 0)       out[i] = d * xi;
  else if (mode == 1)  out[i] = scal[SLOT_ALPHA] * d * xi - xi;
  else                 out[i] = 2.0f * scal[SLOT_ALPHA] * d * xi - 2.0f * xi - xprev[i];
}

// f32 fallback matvec (only if ws too small)
__global__ __launch_bounds__(256) void k_matvec(const float* __restrict__ x,
                                                const float* __restrict__ Q,
                                                const int* __restrict__ ei,
                                                float* __restrict__ out,
                                                const float* __restrict__ scal,
                                                int use_alpha, float smul) {
  const int slot = threadIdx.x >> 5;
  const int lane = threadIdx.x & 31;
  const int e = blockIdx.x * 8 + slot;
  const float factor = use_alpha ? scal[SLOT_ALPHA] * smul : smul;
  const int row = ei[e];
  const int col = ei[EE + e];
  const fv4* __restrict__ x4 = (const fv4*)(x + (size_t)col * DD);
  fv4 xr[8];
#pragma unroll
  for (int k = 0; k < 8; ++k) xr[k] = x4[k];
  const fv4* __restrict__ q4 =
      (const fv4*)(Q + (size_t)e * (DD * DD) + (size_t)lane * DD);
  float acc = 0.0f;
#pragma unroll
  for (int k = 0; k < 8; ++k) {
    fv4 q = q4[k];
    acc = fmaf(q.x, xr[k].x, acc);
    acc = fmaf(q.y, xr[k].y, acc);
    acc = fmaf(q.z, xr[k].z, acc);
    acc = fmaf(q.w, xr[k].w, acc);
  }
  atomicAdd(out + (size_t)row * DD + lane, -factor * acc);
}

#define DOT_BLOCKS 640
__global__ void k_dots(const float* __restrict__ u4, const float* __restrict__ u5,
                       float* __restrict__ scal) {
  float s1 = 0.0f, s2 = 0.0f;
  for (int i = blockIdx.x * 256 + threadIdx.x; i < ND; i += DOT_BLOCKS * 256) {
    float a = u4[i], b = u5[i];
    s1 = fmaf(a, b, s1);
    s2 = fmaf(a, a, s2);
  }
  s1 = wave64_sum(s1);
  s2 = wave64_sum(s2);
  __shared__ float ls1[4], ls2[4];
  int w = threadIdx.x >> 6;
  if ((threadIdx.x & 63) == 0) { ls1[w] = s1; ls2[w] = s2; }
  __syncthreads();
  if (threadIdx.x == 0) {
    atomicAdd(scal + 64, ls1[0] + ls1[1] + ls1[2] + ls1[3]);
    atomicAdd(scal + 64 + 1024, ls2[0] + ls2[1] + ls2[2] + ls2[3]);
  }
}

__global__ void k_alpha(float* __restrict__ scal) {
  float S1 = 0.0f, S2 = 0.0f;
  for (int l = 0; l < 32; ++l) {
    S1 += scal[64 + l * 32];
    S2 += scal[64 + 1024 + l * 32];
  }
  float lam = S1 / S2 / (1.0f + 1e-8f);
  lam = fmaxf(lam, 1.0f);
  scal[SLOT_ALPHA] = 2.0f / (lam + 1e-8f);
}

__global__ __launch_bounds__(256) void k_fuse(
    const float* __restrict__ h,
    const float* __restrict__ T1, const float* __restrict__ T2,
    const float* __restrict__ T3, const float* __restrict__ T4,
    const float* __restrict__ coeffs,
    const float* __restrict__ projW, const float* __restrict__ projb,
    const float* __restrict__ projg, const float* __restrict__ projbeta,
    const float* __restrict__ fusW1, const float* __restrict__ fusb1,
    const float* __restrict__ fusg, const float* __restrict__ fusbeta,
    const float* __restrict__ fusW2, const float* __restrict__ fusb2,
    float* __restrict__ out) {
  __shared__ float s_res[8][3][DD];
  __shared__ float s_p[8][3 * DD];
  __shared__ float s_s[8][DD];
  const int slot = threadIdx.x >> 5;
  const int lane = threadIdx.x & 31;
  const int n = blockIdx.x * 8 + slot;

  float w[3][5];
#pragma unroll
  for (int b = 0; b < 3; ++b) {
    float m = -1e30f;
#pragma unroll
    for (int k = 0; k < 5; ++k) m = fmaxf(m, coeffs[b * 5 + k]);
    float s = 0.0f;
#pragma unroll
    for (int k = 0; k < 5; ++k) { w[b][k] = expf(coeffs[b * 5 + k] - m); s += w[b][k]; }
#pragma unroll
    for (int k = 0; k < 5; ++k) w[b][k] /= s;
  }

  const int idx = n * DD + lane;
  float hd = h[idx], t1 = T1[idx], t2 = T2[idx], t3 = T3[idx], t4 = T4[idx];
#pragma unroll
  for (int b = 0; b < 3; ++b)
    s_res[slot][b][lane] =
        w[b][0] * hd + w[b][1] * t1 + w[b][2] * t2 + w[b][3] * t3 + w[b][4] * t4;
  __syncthreads();

#pragma unroll
  for (int b = 0; b < 3; ++b) {
    float y = projb[b * DD + lane];
#pragma unroll
    for (int j = 0; j < DD; ++j)
      y = fmaf(s_res[slot][b][j], projW[(b * DD + j) * DD + lane], y);
    float mu = g32_sum(y) * (1.0f / DD);
    float d = y - mu;
    float var = g32_sum(d * d) * (1.0f / DD);
    float z = d * rsqrtf(var + LNEPS) * projg[b * DD + lane] + projbeta[b * DD + lane];
    float pb = z / (1.0f + expf(-z));
    s_p[slot][b * DD + lane] = pb;
  }
  __syncthreads();

  float y = fusb1[lane];
#pragma unroll
  for (int j = 0; j < 3 * DD; ++j)
    y = fmaf(s_p[slot][j], fusW1[j * DD + lane], y);
  float mu = g32_sum(y) * (1.0f / DD);
  float d = y - mu;
  float var = g32_sum(d * d) * (1.0f / DD);
  float z = d * rsqrtf(var + LNEPS) * fusg[lane] + fusbeta[lane];
  float sv = z / (1.0f + expf(-z));
  s_s[slot][lane] = sv;
  __syncthreads();

  float o = fusb2[lane];
#pragma unroll
  for (int j = 0; j < DD; ++j)
    o = fmaf(s_s[slot][j], fusW2[j * DD + lane], o);
  out[idx] = hd + o;
}

extern "C" void kernel_launch(void* const* d_in, const int* in_sizes, int n_in,
                              void* d_out, int out_size, void* d_ws, size_t ws_size,
                              hipStream_t stream) {
  (void)in_sizes; (void)n_in; (void)out_size;
  const float* h        = (const float*)d_in[0];
  const float* Q        = (const float*)d_in[1];
  const int*   ei       = (const int*)d_in[2];
  const float* coeffs   = (const float*)d_in[3];
  const float* projW    = (const float*)d_in[4];
  const float* projb    = (const float*)d_in[5];
  const float* projg    = (const float*)d_in[6];
  const float* projbeta = (const float*)d_in[7];
  const float* fusW1    = (const float*)d_in[8];
  const float* fusb1    = (const float*)d_in[9];
  const float* fusg     = (const float*)d_in[10];
  const float* fusbeta  = (const float*)d_in[11];
  const float* fusW2    = (const float*)d_in[12];
  const float* fusb2    = (const float*)d_in[13];
  float* out = (float*)d_out;

  // workspace layout
  const size_t qi_bytes  = (size_t)EE * DD * DD;              // 204.8 MB
  const size_t qs_bytes  = (size_t)EE * DD * sizeof(__half);  // 12.8 MB
  const size_t col_bytes = (size_t)EE * sizeof(int);
  const size_t idx_bytes = (size_t)(2 * NN + 2) * sizeof(int);
  const size_t f32_elems = 6u * (size_t)ND + 2u * NN + SCAL_FLOATS;
  const size_t meta = qi_bytes + qs_bytes + col_bytes + idx_bytes;
  const size_t need = meta + f32_elems * sizeof(float) + 512;
  const bool fast = ws_size >= need;

  char*   Qi8 = (char*)d_ws;
  __half* Qs  = (__half*)((char*)d_ws + qi_bytes);
  int*  cols      = (int*)((char*)d_ws + qi_bytes + qs_bytes);
  int*  row_start = cols + EE;
  int*  cursor    = row_start + NN + 1;
  float* base = fast
      ? (float*)((char*)d_ws + ((meta + 255) & ~(size_t)255))
      : (float*)d_ws;
  float* uA   = base;
  float* uB   = uA + ND;
  float* T1   = uB + ND;
  float* T2   = T1 + ND;
  float* T3   = T2 + ND;
  float* T4   = T3 + ND;
  float* deg  = T4 + ND;              // [NN]
  float* scal = deg + NN;             // [SCAL_FLOATS]
  int*   hist = (int*)(scal + SCAL_FLOATS);  // [NN]

  // zero deg + scal(incl. dot leaves) + hist
  (void)hipMemsetAsync(deg, 0, (2 * (size_t)NN + SCAL_FLOATS) * sizeof(float),
                       stream);

  k_deg<<<(EE + 255) / 256, 256, 0, stream>>>(ei, deg, hist);

  if (fast) {
    // k_genv also pre-fills uB = deg*uA (diag of sweep 1)
    k_genv<<<ND / 256, 256, 0, stream>>>(uA, uB, deg);
    k_scan<<<1, 1024, 0, stream>>>(hist, row_start, cursor);
    // sweep 1 fused with conversion: uB = deg*uA - Q.uA (f32-exact)
    k_cvt_mv<<<EE / 8, 256, 0, stream>>>(uA, Q, ei, cursor, Qi8, Qs, cols, uB);

    // power sweeps 2..5 (int8 gather): uB -> uA -> uB -> uA -> uB
    // 4th sweep (mode 3) also computes u4.u5 and u4.u4 into scal leaves.
    k_gather<<<NN / 4, 256, 0, stream>>>(uB, nullptr, Qi8, Qs, cols,
                                         row_start, deg, scal, scal, uA, 0);
    k_gather<<<NN / 4, 256, 0, stream>>>(uA, nullptr, Qi8, Qs, cols,
                                         row_start, deg, scal, scal, uB, 0);
    k_gather<<<NN / 4, 256, 0, stream>>>(uB, nullptr, Qi8, Qs, cols,
                                         row_start, deg, scal, scal, uA, 0);
    k_gather<<<NN / 4, 256, 0, stream>>>(uA, nullptr, Qi8, Qs, cols,
                                         row_start, deg, scal, scal, uB, 3);
    k_alpha<<<1, 1, 0, stream>>>(scal);

    // Chebyshev: T1 = alpha*L h - h ; T_next = 2*(alpha*L x - x) - xprev
    const float* xin[4]   = {h, T1, T2, T3};
    const float* prevs[4] = {h, h, T1, T2};
    float* touts[4]       = {T1, T2, T3, T4};
    for (int k = 0; k < 4; ++k) {
      k_gather<<<NN / 4, 256, 0, stream>>>(xin[k], prevs[k], Qi8, Qs, cols,
                                           row_start, deg, scal, scal, touts[k],
                                           k == 0 ? 1 : 2);
    }
  } else {
    // f32 atomic-scatter fallback
    k_genv<<<ND / 256, 256, 0, stream>>>(uA, nullptr, deg);
    float* cur = uA;
    float* nxt = uB;
    for (int it = 0; it < 5; ++it) {
      k_pre<<<ND / 256, 256, 0, stream>>>(cur, nullptr, deg, scal, nxt, 0);
      k_matvec<<<EE / 8, 256, 0, stream>>>(cur, Q, ei, nxt, scal, 0, 1.0f);
      float* t = cur; cur = nxt; nxt = t;
    }
    k_dots<<<DOT_BLOCKS, 256, 0, stream>>>(nxt, cur, scal);
    k_alpha<<<1, 1, 0, stream>>>(scal);
    const float* xin[4]   = {h, T1, T2, T3};
    const float* prevs[4] = {nullptr, h, T1, T2};
    float* touts[4]       = {T1, T2, T3, T4};
    for (int k = 0; k < 4; ++k) {
      k_pre<<<ND / 256, 256, 0, stream>>>(xin[k], prevs[k], deg, scal, touts[k],
                                          k == 0 ? 1 : 2);
      k_matvec<<<EE / 8, 256, 0, stream>>>(xin[k], Q, ei, touts[k], scal, 1,
                                           k == 0 ? 1.0f : 2.0f);
    }
  }

  k_fuse<<<NN / 8, 256, 0, stream>>>(h, T1, T2, T3, T4, coeffs,
                                     projW, projb, projg, projbeta,
                                     fusW1, fusb1, fusg, fusbeta,
                                     fusW2, fusb2, out);
}

// Round 15
// 911.197 us; speedup vs baseline: 1.1654x; 1.0311x over previous
//
#include <hip/hip_runtime.h>
#include <hip/hip_fp16.h>
#include <math.h>

#define NN 40000
#define EE 200000
#define DD 32
#define ND (NN * DD)        // 1,280,000
#define LNEPS 1e-5f

typedef float    fv4 __attribute__((ext_vector_type(4)));
typedef unsigned uv4 __attribute__((ext_vector_type(4)));

// scal layout: [48]=alpha; dot leaves: s1 at 64+l*32, s2 at 64+1024+l*32
#define SLOT_ALPHA 48
#define SCAL_FLOATS (64 + 2048 + 64)

__device__ __forceinline__ void threefry2x32(unsigned k0, unsigned k1,
                                             unsigned x0, unsigned x1,
                                             unsigned& o0, unsigned& o1) {
  const unsigned k2 = k0 ^ k1 ^ 0x1BD11BDAu;
  unsigned v0 = x0 + k0, v1 = x1 + k1;
#define TF_ROUND(r) { v0 += v1; v1 = (v1 << (r)) | (v1 >> (32 - (r))); v1 ^= v0; }
  TF_ROUND(13) TF_ROUND(15) TF_ROUND(26) TF_ROUND(6)
  v0 += k1; v1 += k2 + 1u;
  TF_ROUND(17) TF_ROUND(29) TF_ROUND(16) TF_ROUND(24)
  v0 += k2; v1 += k0 + 2u;
  TF_ROUND(13) TF_ROUND(15) TF_ROUND(26) TF_ROUND(6)
  v0 += k0; v1 += k1 + 3u;
  TF_ROUND(17) TF_ROUND(29) TF_ROUND(16) TF_ROUND(24)
  v0 += k1; v1 += k2 + 4u;
  TF_ROUND(13) TF_ROUND(15) TF_ROUND(26) TF_ROUND(6)
  v0 += k2; v1 += k0 + 5u;
#undef TF_ROUND
  o0 = v0; o1 = v1;
}

__device__ __forceinline__ float wave64_sum(float x) {
  for (int o = 32; o > 0; o >>= 1) x += __shfl_xor(x, o, 64);
  return x;
}
__device__ __forceinline__ float g32_sum(float x) {
  for (int o = 16; o > 0; o >>= 1) x += __shfl_xor(x, o, 32);
  return x;
}

// deg (float, both endpoints) + hist (int, row occurrences)
__global__ void k_deg(const int* __restrict__ ei, float* __restrict__ deg,
                      int* __restrict__ hist) {
  int e = blockIdx.x * 256 + threadIdx.x;
  if (e < EE) {
    int r = ei[e];
    atomicAdd(deg + r, 1.0f);
    atomicAdd(deg + ei[EE + e], 1.0f);
    atomicAdd(hist + r, 1);
  }
}

// single-block exclusive scan over hist[NN] -> row_start[NN+1], cursor[NN]
__global__ __launch_bounds__(1024) void k_scan(const int* __restrict__ hist,
                                               int* __restrict__ row_start,
                                               int* __restrict__ cursor) {
  __shared__ int part[1024];
  const int t = threadIdx.x;
  const int base = t * 40;
  int s = 0;
  for (int i = base; i < base + 40 && i < NN; ++i) s += hist[i];
  part[t] = s;
  __syncthreads();
  for (int off = 1; off < 1024; off <<= 1) {
    int v = (t >= off) ? part[t - off] : 0;
    __syncthreads();
    part[t] += v;
    __syncthreads();
  }
  int ex = (t == 0) ? 0 : part[t - 1];
  for (int i = base; i < base + 40 && i < NN; ++i) {
    row_start[i] = ex;
    cursor[i] = ex;
    ex += hist[i];
  }
  if (t == 0) row_start[NN] = EE;
}

// v0 = N(0,1) via exact JAX threefry pipeline; also pre-fills vpre = deg*v
// (diag of power sweep 1, completed by k_cvt_mv's scatter).
__global__ void k_genv(float* __restrict__ v, float* __restrict__ vpre,
                       const float* __restrict__ deg) {
  int i = blockIdx.x * 256 + threadIdx.x;
  unsigned o0, o1;
  threefry2x32(0u, 42u, 0u, (unsigned)i, o0, o1);
  unsigned bits = o1;
  float f = __uint_as_float((bits >> 9) | 0x3f800000u) - 1.0f;
  const float lo = -0.99999994f;
  float u = fmaxf(lo, f * 2.0f + lo);
  float val = 1.41421354f * erfinvf(u);
  v[i] = val;
  if (vpre) vpre[i] = deg[i >> 5] * val;
}

__device__ __forceinline__ int clamp8(float q) {
  int v = (int)rintf(q);
  return v < -127 ? -127 : (v > 127 ? 127 : v);
}
__device__ __forceinline__ unsigned pack4v(fv4 q, float inv) {
  int q0 = clamp8(q.x * inv), q1 = clamp8(q.y * inv),
      q2 = clamp8(q.z * inv), q3 = clamp8(q.w * inv);
  return (q0 & 255) | ((q1 & 255) << 8) | ((q2 & 255) << 16) | ((q3 & 255) << 24);
}
__device__ __forceinline__ void dp4(unsigned u, fv4 xv, float& acc) {
  acc = fmaf((float)(signed char)(u),        xv.x, acc);
  acc = fmaf((float)(signed char)(u >> 8),   xv.y, acc);
  acc = fmaf((float)(signed char)(u >> 16),  xv.z, acc);
  acc = fmaf((float)(signed char)(u >> 24),  xv.w, acc);
}

// Fused: Q -> int8 sorted-CSR conversion AND power sweep 1 (f32 dot,
// atomic scatter of -Q.x into out pre-filled with deg*x by k_genv).
__global__ __launch_bounds__(256) void k_cvt_mv(const float* __restrict__ x,
                                                const float* __restrict__ Q,
                                                const int* __restrict__ ei,
                                                int* __restrict__ cursor,
                                                char* __restrict__ Qi8,
                                                __half* __restrict__ Qs,
                                                int* __restrict__ cols,
                                                float* __restrict__ out) {
  const int slot = threadIdx.x >> 5;
  const int lane = threadIdx.x & 31;
  const int e = blockIdx.x * 8 + slot;  // EE % 8 == 0
  const int row = ei[e];
  const int col = ei[EE + e];
  int pos = 0;
  if (lane == 0) pos = atomicAdd(cursor + row, 1);
  pos = __shfl(pos, 0, 32);
  const fv4* __restrict__ x4 = (const fv4*)(x + (size_t)col * DD);
  fv4 xr[8];
#pragma unroll
  for (int k = 0; k < 8; ++k) xr[k] = x4[k];
  const fv4* __restrict__ q4 =
      (const fv4*)(Q + (size_t)e * (DD * DD) + (size_t)lane * DD);
  fv4 qf[8];
#pragma unroll
  for (int k = 0; k < 8; ++k) qf[k] = __builtin_nontemporal_load(q4 + k);
  float acc = 0.0f;
#pragma unroll
  for (int k = 0; k < 8; ++k) {
    acc = fmaf(qf[k].x, xr[k].x, acc);
    acc = fmaf(qf[k].y, xr[k].y, acc);
    acc = fmaf(qf[k].z, xr[k].z, acc);
    acc = fmaf(qf[k].w, xr[k].w, acc);
  }
  float m = 0.0f;
#pragma unroll
  for (int k = 0; k < 8; ++k) {
    m = fmaxf(m, fmaxf(fmaxf(fabsf(qf[k].x), fabsf(qf[k].y)),
                       fmaxf(fabsf(qf[k].z), fabsf(qf[k].w))));
  }
  __half sh = __float2half(m * (1.0f / 127.0f));
  float s = __half2float(sh);
  float inv = (s > 0.0f) ? 1.0f / s : 0.0f;
  uv4 pa, pb;
  pa.x = pack4v(qf[0], inv); pa.y = pack4v(qf[1], inv);
  pa.z = pack4v(qf[2], inv); pa.w = pack4v(qf[3], inv);
  pb.x = pack4v(qf[4], inv); pb.y = pack4v(qf[5], inv);
  pb.z = pack4v(qf[6], inv); pb.w = pack4v(qf[7], inv);
  uv4* __restrict__ qs = (uv4*)(Qi8 + (size_t)pos * (DD * DD) + (size_t)lane * DD);
  qs[0] = pa;   // cached — later sweeps get ~45% L3 hits on this copy
  qs[1] = pb;
  Qs[pos * DD + lane] = sh;
  if (lane == 0) cols[pos] = col;
  atomicAdd(out + (size_t)row * DD + lane, -acc);
}

#define CHUNK 16

// Merged two-chain gather: blocks [0,NB) power chain, [NB,2NB) Krylov chain.
// Both compute plain M x = deg*x - Qoff (no alpha anywhere).
// do_dots: power half also accumulates s1 += out.x, s2 += x.x into leaves.
__global__ __launch_bounds__(256) void k_gather2(const float* __restrict__ px,
                                                 float* __restrict__ pout,
                                                 const float* __restrict__ kxv,
                                                 float* __restrict__ kout,
                                                 const char* __restrict__ Qi8,
                                                 const __half* __restrict__ Qs,
                                                 const int* __restrict__ cols,
                                                 const int* __restrict__ row_start,
                                                 const float* __restrict__ deg,
                                                 float* __restrict__ dots,
                                                 int do_dots) {
  __shared__ float lds[4][CHUNK][DD];    // 8 KB
  __shared__ float d1[4], d2[4];
  const int NB = NN / 4;
  const bool isk = blockIdx.x >= NB;
  const int bid = isk ? blockIdx.x - NB : blockIdx.x;
  const float* __restrict__ x = isk ? kxv : px;
  float* __restrict__ out = isk ? kout : pout;

  const int wid  = threadIdx.x >> 6;
  const int lane = threadIdx.x & 63;
  const int half = lane >> 5;
  const int d    = lane & 31;
  const int r = bid * 4 + wid;
  const int beg = row_start[r];
  const int end = row_start[r + 1];
  const int degree = end - beg;

  const size_t idx = (size_t)r * DD + d;
  const float xi = x[idx];
  const float dv = deg[r];

  float acc = 0.0f;
  for (int chunk = 0; chunk < degree; chunk += CHUNK) {
    const int nchunk = min(CHUNK, degree - chunk);
    int myc = (lane < nchunk) ? cols[beg + chunk + lane] : 0;
    {
      const int el = lane >> 2;
      const int pt = lane & 3;
      if (el < nchunk) {
        const int c = __shfl(myc, el, 64);
        const fv4* __restrict__ xs = (const fv4*)(x + (size_t)c * DD);
        fv4 a = xs[pt * 2];
        fv4 b = xs[pt * 2 + 1];
        fv4* __restrict__ dst = (fv4*)&lds[wid][el][pt * 8];
        dst[0] = a;
        dst[1] = b;
      }
    }
    uv4 a0 = {0,0,0,0}, b0 = {0,0,0,0}, a1 = {0,0,0,0}, b1 = {0,0,0,0};
    float s0 = 0.0f, s1 = 0.0f;
#define LOADQ(PP, A, B, S)                                                    \
    if ((PP) < nchunk) {                                                      \
      const size_t pos = (size_t)(beg + chunk + (PP));                        \
      const uv4* __restrict__ q8 =                                            \
          (const uv4*)(Qi8 + pos * (DD * DD) + (size_t)d * DD);               \
      A = q8[0]; B = q8[1];                                                   \
      S = __half2float(Qs[pos * DD + d]);                                     \
    }
    LOADQ(half, a0, b0, s0)
    LOADQ(2 + half, a1, b1, s1)
    for (int p0 = 0; p0 < nchunk; p0 += 2) {
      uv4 a2 = {0,0,0,0}, b2 = {0,0,0,0};
      float s2 = 0.0f;
      LOADQ(p0 + 4 + half, a2, b2, s2)
      const int p = p0 + half;
      if (p < nchunk) {
        const fv4* __restrict__ xl = (const fv4*)&lds[wid][p][0];
        fv4 xr[8];
#pragma unroll
        for (int k = 0; k < 8; ++k) xr[k] = xl[k];
        float dot = 0.0f;
        dp4(a0.x, xr[0], dot); dp4(a0.y, xr[1], dot);
        dp4(a0.z, xr[2], dot); dp4(a0.w, xr[3], dot);
        dp4(b0.x, xr[4], dot); dp4(b0.y, xr[5], dot);
        dp4(b0.z, xr[6], dot); dp4(b0.w, xr[7], dot);
        acc = fmaf(s0, dot, acc);
      }
      a0 = a1; b0 = b1; s0 = s1;
      a1 = a2; b1 = b2; s1 = s2;
    }
#undef LOADQ
  }
  acc += __shfl_xor(acc, 32, 64);

  const float o = dv * xi - acc;
  if (half == 0) out[idx] = o;

  if (!isk && do_dots) {
    float p1 = (half == 0) ? o * xi : 0.0f;
    float p2 = (half == 0) ? xi * xi : 0.0f;
    p1 = wave64_sum(p1);
    p2 = wave64_sum(p2);
    if ((threadIdx.x & 63) == 0) { d1[wid] = p1; d2[wid] = p2; }
    __syncthreads();
    if (threadIdx.x == 0) {
      const int leaf = bid & 31;
      atomicAdd(dots + 64 + leaf * 32, d1[0] + d1[1] + d1[2] + d1[3]);
      atomicAdd(dots + 64 + 1024 + leaf * 32, d2[0] + d2[1] + d2[2] + d2[3]);
    }
  }
}

// ---- fallback pieces (ws too small): f32 scatter ----
__global__ void k_pre(const float* __restrict__ x, const float* __restrict__ deg,
                      float* __restrict__ out) {
  int i = blockIdx.x * 256 + threadIdx.x;
  out[i] = deg[i >> 5] * x[i];
}

__global__ __launch_bounds__(256) void k_matvec(const float* __restrict__ x,
                                                const float* __restrict__ Q,
                                                const int* __restrict__ ei,
                                                float* __restrict__ out) {
  const int slot = threadIdx.x >> 5;
  const int lane = threadIdx.x & 31;
  const int e = blockIdx.x * 8 + slot;
  const int row = ei[e];
  const int col = ei[EE + e];
  const fv4* __restrict__ x4 = (const fv4*)(x + (size_t)col * DD);
  fv4 xr[8];
#pragma unroll
  for (int k = 0; k < 8; ++k) xr[k] = x4[k];
  const fv4* __restrict__ q4 =
      (const fv4*)(Q + (size_t)e * (DD * DD) + (size_t)lane * DD);
  float acc = 0.0f;
#pragma unroll
  for (int k = 0; k < 8; ++k) {
    fv4 q = q4[k];
    acc = fmaf(q.x, xr[k].x, acc);
    acc = fmaf(q.y, xr[k].y, acc);
    acc = fmaf(q.z, xr[k].z, acc);
    acc = fmaf(q.w, xr[k].w, acc);
  }
  atomicAdd(out + (size_t)row * DD + lane, -acc);
}

#define DOT_BLOCKS 640
__global__ void k_dots(const float* __restrict__ u4, const float* __restrict__ u5,
                       float* __restrict__ scal) {
  float s1 = 0.0f, s2 = 0.0f;
  for (int i = blockIdx.x * 256 + threadIdx.x; i < ND; i += DOT_BLOCKS * 256) {
    float a = u4[i], b = u5[i];
    s1 = fmaf(a, b, s1);
    s2 = fmaf(a, a, s2);
  }
  s1 = wave64_sum(s1);
  s2 = wave64_sum(s2);
  __shared__ float ls1[4], ls2[4];
  int w = threadIdx.x >> 6;
  if ((threadIdx.x & 63) == 0) { ls1[w] = s1; ls2[w] = s2; }
  __syncthreads();
  if (threadIdx.x == 0) {
    atomicAdd(scal + 64, ls1[0] + ls1[1] + ls1[2] + ls1[3]);
    atomicAdd(scal + 64 + 1024, ls2[0] + ls2[1] + ls2[2] + ls2[3]);
  }
}

__global__ void k_alpha(float* __restrict__ scal) {
  float S1 = 0.0f, S2 = 0.0f;
  for (int l = 0; l < 32; ++l) {
    S1 += scal[64 + l * 32];
    S2 += scal[64 + 1024 + l * 32];
  }
  float lam = S1 / S2 / (1.0f + 1e-8f);
  lam = fmaxf(lam, 1.0f);
  scal[SLOT_ALPHA] = 2.0f / (lam + 1e-8f);
}

// Fusion epilogue, Krylov form: T_k reconstructed from y_j = alpha^j * W_j.
// T0=[1,0,0,0,0] T1=[-1,1,0,0,0] T2=[1,-4,2,0,0]
// T3=[-1,9,-12,4,0] T4=[1,-16,40,-32,8]   (coeffs on y_0..y_4; W_0 = h)
__global__ __launch_bounds__(256) void k_fuse(
    const float* __restrict__ h,
    const float* __restrict__ W1, const float* __restrict__ W2,
    const float* __restrict__ W3, const float* __restrict__ W4,
    const float* __restrict__ scal,
    const float* __restrict__ coeffs,
    const float* __restrict__ projW, const float* __restrict__ projb,
    const float* __restrict__ projg, const float* __restrict__ projbeta,
    const float* __restrict__ fusW1, const float* __restrict__ fusb1,
    const float* __restrict__ fusg, const float* __restrict__ fusbeta,
    const float* __restrict__ fusW2, const float* __restrict__ fusb2,
    float* __restrict__ out) {
  __shared__ float s_res[8][3][DD];
  __shared__ float s_p[8][3 * DD];
  __shared__ float s_s[8][DD];
  const int slot = threadIdx.x >> 5;
  const int lane = threadIdx.x & 31;
  const int n = blockIdx.x * 8 + slot;

  float w[3][5];
#pragma unroll
  for (int b = 0; b < 3; ++b) {
    float m = -1e30f;
#pragma unroll
    for (int k = 0; k < 5; ++k) m = fmaxf(m, coeffs[b * 5 + k]);
    float s = 0.0f;
#pragma unroll
    for (int k = 0; k < 5; ++k) { w[b][k] = expf(coeffs[b * 5 + k] - m); s += w[b][k]; }
#pragma unroll
    for (int k = 0; k < 5; ++k) w[b][k] /= s;
  }

  // Chebyshev expansion matrix (T_k in terms of y_j)
  const float C[5][5] = {
      { 1.0f,   0.0f,   0.0f,   0.0f,  0.0f},
      {-1.0f,   1.0f,   0.0f,   0.0f,  0.0f},
      { 1.0f,  -4.0f,   2.0f,   0.0f,  0.0f},
      {-1.0f,   9.0f, -12.0f,   4.0f,  0.0f},
      { 1.0f, -16.0f,  40.0f, -32.0f,  8.0f}};
  float cb[3][5];
#pragma unroll
  for (int b = 0; b < 3; ++b)
#pragma unroll
    for (int j = 0; j < 5; ++j) {
      float c = 0.0f;
#pragma unroll
      for (int k = 0; k < 5; ++k) c = fmaf(w[b][k], C[k][j], c);
      cb[b][j] = c;
    }

  const float alpha = scal[SLOT_ALPHA];
  const float a1 = alpha, a2 = a1 * alpha, a3 = a2 * alpha, a4 = a3 * alpha;

  const int idx = n * DD + lane;
  const float hd = h[idx];
  float y[5];
  y[0] = hd;
  y[1] = a1 * W1[idx];
  y[2] = a2 * W2[idx];
  y[3] = a3 * W3[idx];
  y[4] = a4 * W4[idx];
#pragma unroll
  for (int b = 0; b < 3; ++b) {
    float res = 0.0f;
#pragma unroll
    for (int j = 0; j < 5; ++j) res = fmaf(cb[b][j], y[j], res);
    s_res[slot][b][lane] = res;
  }
  __syncthreads();

#pragma unroll
  for (int b = 0; b < 3; ++b) {
    float yv = projb[b * DD + lane];
#pragma unroll
    for (int j = 0; j < DD; ++j)
      yv = fmaf(s_res[slot][b][j], projW[(b * DD + j) * DD + lane], yv);
    float mu = g32_sum(yv) * (1.0f / DD);
    float dv = yv - mu;
    float var = g32_sum(dv * dv) * (1.0f / DD);
    float z = dv * rsqrtf(var + LNEPS) * projg[b * DD + lane] + projbeta[b * DD + lane];
    float pb = z / (1.0f + expf(-z));
    s_p[slot][b * DD + lane] = pb;
  }
  __syncthreads();

  float yv = fusb1[lane];
#pragma unroll
  for (int j = 0; j < 3 * DD; ++j)
    yv = fmaf(s_p[slot][j], fusW1[j * DD + lane], yv);
  float mu = g32_sum(yv) * (1.0f / DD);
  float dv = yv - mu;
  float var = g32_sum(dv * dv) * (1.0f / DD);
  float z = dv * rsqrtf(var + LNEPS) * fusg[lane] + fusbeta[lane];
  float sv = z / (1.0f + expf(-z));
  s_s[slot][lane] = sv;
  __syncthreads();

  float o = fusb2[lane];
#pragma unroll
  for (int j = 0; j < DD; ++j)
    o = fmaf(s_s[slot][j], fusW2[j * DD + lane], o);
  out[idx] = hd + o;
}

extern "C" void kernel_launch(void* const* d_in, const int* in_sizes, int n_in,
                              void* d_out, int out_size, void* d_ws, size_t ws_size,
                              hipStream_t stream) {
  (void)in_sizes; (void)n_in; (void)out_size;
  const float* h        = (const float*)d_in[0];
  const float* Q        = (const float*)d_in[1];
  const int*   ei       = (const int*)d_in[2];
  const float* coeffs   = (const float*)d_in[3];
  const float* projW    = (const float*)d_in[4];
  const float* projb    = (const float*)d_in[5];
  const float* projg    = (const float*)d_in[6];
  const float* projbeta = (const float*)d_in[7];
  const float* fusW1    = (const float*)d_in[8];
  const float* fusb1    = (const float*)d_in[9];
  const float* fusg     = (const float*)d_in[10];
  const float* fusbeta  = (const float*)d_in[11];
  const float* fusW2    = (const float*)d_in[12];
  const float* fusb2    = (const float*)d_in[13];
  float* out = (float*)d_out;

  // workspace layout
  const size_t qi_bytes  = (size_t)EE * DD * DD;              // 204.8 MB
  const size_t qs_bytes  = (size_t)EE * DD * sizeof(__half);  // 12.8 MB
  const size_t col_bytes = (size_t)EE * sizeof(int);
  const size_t idx_bytes = (size_t)(2 * NN + 2) * sizeof(int);
  const size_t f32_elems = 6u * (size_t)ND + 2u * NN + SCAL_FLOATS;
  const size_t meta = qi_bytes + qs_bytes + col_bytes + idx_bytes;
  const size_t need = meta + f32_elems * sizeof(float) + 512;
  const bool fast = ws_size >= need;

  char*   Qi8 = (char*)d_ws;
  __half* Qs  = (__half*)((char*)d_ws + qi_bytes);
  int*  cols      = (int*)((char*)d_ws + qi_bytes + qs_bytes);
  int*  row_start = cols + EE;
  int*  cursor    = row_start + NN + 1;
  float* base = fast
      ? (float*)((char*)d_ws + ((meta + 255) & ~(size_t)255))
      : (float*)d_ws;
  float* uA   = base;
  float* uB   = uA + ND;
  float* W1   = uB + ND;
  float* W2   = W1 + ND;
  float* W3   = W2 + ND;
  float* W4   = W3 + ND;
  float* deg  = W4 + ND;              // [NN]
  float* scal = deg + NN;             // [SCAL_FLOATS]
  int*   hist = (int*)(scal + SCAL_FLOATS);  // [NN]

  (void)hipMemsetAsync(deg, 0, (2 * (size_t)NN + SCAL_FLOATS) * sizeof(float),
                       stream);

  k_deg<<<(EE + 255) / 256, 256, 0, stream>>>(ei, deg, hist);

  if (fast) {
    // RNG + uB = deg*uA (diag of sweep 1)
    k_genv<<<ND / 256, 256, 0, stream>>>(uA, uB, deg);
    k_scan<<<1, 1024, 0, stream>>>(hist, row_start, cursor);
    // sweep 1 fused with conversion: uB = deg*uA - Q.uA (u1, f32-exact)
    k_cvt_mv<<<EE / 8, 256, 0, stream>>>(uA, Q, ei, cursor, Qi8, Qs, cols, uB);

    // 4 merged dispatches: power chain u2..u5 ∥ Krylov chain W1..W4
    const int G2 = 2 * (NN / 4);
    k_gather2<<<G2, 256, 0, stream>>>(uB, uA, h,  W1, Qi8, Qs, cols,
                                      row_start, deg, scal, 0);
    k_gather2<<<G2, 256, 0, stream>>>(uA, uB, W1, W2, Qi8, Qs, cols,
                                      row_start, deg, scal, 0);
    k_gather2<<<G2, 256, 0, stream>>>(uB, uA, W2, W3, Qi8, Qs, cols,
                                      row_start, deg, scal, 0);
    k_gather2<<<G2, 256, 0, stream>>>(uA, uB, W3, W4, Qi8, Qs, cols,
                                      row_start, deg, scal, 1);  // + dots(u4,u5)
    k_alpha<<<1, 1, 0, stream>>>(scal);
  } else {
    // f32 atomic-scatter fallback: power chain then Krylov chain
    k_genv<<<ND / 256, 256, 0, stream>>>(uA, nullptr, deg);
    float* cur = uA;
    float* nxt = uB;
    for (int it = 0; it < 5; ++it) {
      k_pre<<<ND / 256, 256, 0, stream>>>(cur, deg, nxt);
      k_matvec<<<EE / 8, 256, 0, stream>>>(cur, Q, ei, nxt);
      float* t = cur; cur = nxt; nxt = t;
    }
    k_dots<<<DOT_BLOCKS, 256, 0, stream>>>(nxt, cur, scal);
    k_alpha<<<1, 1, 0, stream>>>(scal);
    const float* xin[4] = {h, W1, W2, W3};
    float* wout[4]      = {W1, W2, W3, W4};
    for (int k = 0; k < 4; ++k) {
      k_pre<<<ND / 256, 256, 0, stream>>>(xin[k], deg, wout[k]);
      k_matvec<<<EE / 8, 256, 0, stream>>>(xin[k], Q, ei, wout[k]);
    }
  }

  k_fuse<<<NN / 8, 256, 0, stream>>>(h, W1, W2, W3, W4, scal, coeffs,
                                     projW, projb, projg, projbeta,
                                     fusW1, fusb1, fusg, fusbeta,
                                     fusW2, fusb2, out);
}